// Round 16
// baseline (103.969 us; speedup 1.0000x reference)
//
#include <hip/hip_runtime.h>

// LNCC multi-scale loss, fp32, (4,1,144,144,144) -> scalar.
// A(K=9,ST=2), B(K=18,ST=4): all taps on even coords -> even-grid volume.
//   A = 9^3 box stride 1 on even grid; B = 18^3 = eight 9^3 boxes =>
//   B-XY = 4 adds over A's XY sums (b2a->b2b); B-Z from compact b2b.
// C(K=36,ST=9): cX (k1, LDS-staged) -> cYL (k2, LDS-staged per (b,z)) -> cZ.
// No same-address atomics; reducers write partial[blk]; k4 sums.
// k1: aXY + cX 1:3 ROLE-INTERLEAVED (one input sweep); aXY Y-phase 8-slide
// k2: aZ CHUNK=16 +LNCC->pA | bXY vec | cYL (LDS, no tap re-reads)
// k3: bZ vec+LNCC->pB | cZ+LNCC->pC
// k4: weighted reduce -> out

constexpr int BATCH = 4;
constexpr int DIM   = 144;
constexpr int NROWS = BATCH * DIM * DIM;        // 82944
constexpr float EPS = 1e-5f;

constexpr int N1C  = NROWS * 9;                 //   746,496 (C X-out)
constexpr int N2Ae = BATCH * 72 * 64 * 64;      // 1,179,648 (A XY-out)
constexpr int N2Be = BATCH * 72 * 28 * 28;      //   225,792 (B XY-out)
constexpr int N2C  = BATCH * DIM * 9 * 9;       //    46,656 (C Y-out)

// ======================= shared device helpers ==============================

__device__ __forceinline__ float lncc_val(const float s[5], float inv_numel) {
    float cross = s[4] - s[0] * s[1] * inv_numel;
    float ivar  = s[2] - s[0] * s[0] * inv_numel;
    float tvar  = s[3] - s[1] * s[1] * inv_numel;
    return (cross * cross) / (ivar * tvar + EPS);
}

__device__ __forceinline__ void block_reduce_store(float acc, float* slot) {
    #pragma unroll
    for (int off = 32; off > 0; off >>= 1) acc += __shfl_down(acc, off, 64);
    __shared__ float sm[4];
    int lane = threadIdx.x & 63, wid = threadIdx.x >> 6;
    if (lane == 0) sm[wid] = acc;
    __syncthreads();
    if (threadIdx.x == 0) *slot = sm[0] + sm[1] + sm[2] + sm[3];
}

// ======================= k1 bodies ==========================================
// aXY: one even-z plane, one 16-wide xo chunk; X-phase float4 taps (proven);
// Y-phase: 8-slide, 320 items -> all 256 threads active.

__device__ void aXY_body(int blk, const float* __restrict__ in,
                         const float* __restrict__ tg,
                         float* __restrict__ b2a, float* xs)
{
    const int p  = blk >> 2;            // b*72 + ez
    const int c  = blk & 3;
    const int b  = p / 72;
    const int ez = p % 72;
    const int xo0 = c * 16;
    const size_t gpl = (size_t)(b * DIM + 2 * ez) * (DIM * DIM);
    const int t = threadIdx.x;

    // ---- X: items (yp 0..71, dp 0..7) -> outputs dx0=2dp, dx0+1 ----
    for (int i = t; i < 576; i += 256) {
        int yp = i >> 3, dp = i & 7;
        int dx0 = dp * 2;
        int e0  = xo0 + dx0;
        const float* rowa = in + gpl + (size_t)(2 * yp) * DIM;
        const float* rowb = tg + gpl + (size_t)(2 * yp) * DIM;
        const float4* ga = (const float4*)rowa + (e0 >> 1);
        const float4* gb = (const float4*)rowb + (e0 >> 1);
        float ea[10], eb[10];
        #pragma unroll
        for (int k = 0; k < 5; ++k) {
            float4 A = ga[k]; ea[2 * k] = A.x; ea[2 * k + 1] = A.z;
            float4 B = gb[k]; eb[2 * k] = B.x; eb[2 * k + 1] = B.z;
        }
        float* xr = &xs[yp * 82 + dx0];
        #pragma unroll
        for (int q = 0; q < 5; ++q) {
            float2 sq; sq.x = 0.f; sq.y = 0.f;
            #pragma unroll
            for (int j = 0; j < 9; ++j) {
                float a0 = ea[j],     b0 = eb[j];
                float a1 = ea[j + 1], b1 = eb[j + 1];
                float v0, v1;
                if (q == 0)      { v0 = a0;      v1 = a1; }
                else if (q == 1) { v0 = b0;      v1 = b1; }
                else if (q == 2) { v0 = a0 * a0; v1 = a1 * a1; }
                else if (q == 3) { v0 = b0 * b0; v1 = b1 * b1; }
                else             { v0 = a0 * b0; v1 = a1 * b1; }
                sq.x += v0; sq.y += v1;
            }
            *(float2*)&xr[q * 16] = sq;
        }
    }
    __syncthreads();

    // ---- Y: items (q 0..4, ch 0..7, dp 0..7) = 320; slide over 8 yo ----
    for (int it = t; it < 320; it += 256) {
        int dp = it & 7;
        int ch = (it >> 3) & 7;
        int q  = it >> 6;
        int dx0 = 2 * dp, yo0 = ch * 8;
        const float2* xp2 = (const float2*)xs + ((q * 16 + dx0) >> 1);
        float2 s; s.x = 0.f; s.y = 0.f;
        #pragma unroll
        for (int j = 0; j < 9; ++j) {
            float2 v = xp2[(yo0 + j) * 41];
            s.x += v.x; s.y += v.y;
        }
        float2* ob = (float2*)(b2a + (size_t)q * N2Ae
                               + ((size_t)p * 64 + yo0) * 64 + xo0 + dx0);
        ob[0] = s;
        #pragma unroll
        for (int i2 = 1; i2 < 8; ++i2) {
            float2 vn = xp2[(yo0 + i2 + 8) * 41];
            float2 vo = xp2[(yo0 + i2 - 1) * 41];
            s.x += vn.x - vo.x; s.y += vn.y - vo.y;
            ob[(size_t)i2 * 32] = s;
        }
    }
}

constexpr int CXROWS   = 24;
constexpr int CXSTRIDE = 292;                    // dwords per LDS row

__device__ void cX_body(int blk, const float* __restrict__ in,
                        const float* __restrict__ tg,
                        float* __restrict__ b1c, float* lv)
{
    const int t = threadIdx.x;
    const int row0 = blk * CXROWS;
    const float4* gin = (const float4*)(in + (size_t)row0 * DIM);
    const float4* gtg = (const float4*)(tg + (size_t)row0 * DIM);
    for (int i4 = t; i4 < CXROWS * 36; i4 += 256) {
        int rr = i4 / 36, k = i4 % 36;
        float4 A = gin[i4], B = gtg[i4];
        float4* d = (float4*)&lv[rr * CXSTRIDE + k * 8];
        float4 w0; w0.x = A.x; w0.y = B.x; w0.z = A.y; w0.w = B.y;
        float4 w1; w1.x = A.z; w1.y = B.z; w1.z = A.w; w1.w = B.w;
        d[0] = w0; d[1] = w1;
    }
    __syncthreads();
    if (t < CXROWS * 9) {
        int rr = t / 9, xo = t % 9;
        const float2* pp = (const float2*)&lv[rr * CXSTRIDE] + xo * 9;
        float s0 = 0.f, s1 = 0.f, s2 = 0.f, s3 = 0.f, s4 = 0.f;
        #pragma unroll
        for (int j = 0; j < 36; ++j) {
            float2 ab = pp[2 * j];
            float a = ab.x, bb = ab.y;
            s0 += a; s1 += bb; s2 += a * a; s3 += bb * bb; s4 += a * bb;
        }
        int o = (row0 + rr) * 9 + xo;
        b1c[o] = s0; b1c[N1C + o] = s1; b1c[2 * N1C + o] = s2;
        b1c[3 * N1C + o] = s3; b1c[4 * N1C + o] = s4;
    }
}

constexpr int B_AXY = BATCH * 72 * 4;        // 1152
constexpr int B_CX  = NROWS / CXROWS;        // 3456 = 3 * B_AXY
constexpr int SM1   = CXROWS * CXSTRIDE;     // 7008 floats (28 KB) >= 72*82

// 1:3 interleave: block 4g+0 -> aXY(g); blocks 4g+{1,2,3} -> cX(3g+sub-1)
__global__ __launch_bounds__(256) void k1(const float* __restrict__ in,
                                          const float* __restrict__ tg,
                                          float* __restrict__ b2a,
                                          float* __restrict__ b1c)
{
    __shared__ float smem[SM1];
    int grp = blockIdx.x >> 2, sub = blockIdx.x & 3;
    if (sub == 0) aXY_body(grp, in, tg, b2a, smem);
    else          cX_body(grp * 3 + sub - 1, in, tg, b1c, smem);
}

// ======================= k2 bodies ==========================================

// A: Z box-sum + LNCC, sliding CHUNK=16 (read redundancy 1.5x) -> pA[blk]
__device__ __forceinline__ void aZ_body(int blk, const float* __restrict__ b2a,
                                        float* __restrict__ pA)
{
    int tid = blk * 256 + threadIdx.x;
    float acc = 0.f;
    {
        int xo = tid & 63;
        int yo = (tid >> 6) & 63;
        int ch = (tid >> 12) & 3;
        int b  = tid >> 14;
        const int zo0 = ch * 16;
        const int OO = 64 * 64;
        const float* base = b2a + (size_t)b * 72 * OO + yo * 64 + xo;

        float s[5] = {0.f, 0.f, 0.f, 0.f, 0.f};
        #pragma unroll
        for (int j = 0; j < 9; ++j) {
            #pragma unroll
            for (int q = 0; q < 5; ++q)
                s[q] += base[(size_t)q * N2Ae + (zo0 + j) * OO];
        }
        acc += lncc_val(s, 1.0f / 729.0f);
        #pragma unroll
        for (int i = 1; i < 16; ++i) {
            #pragma unroll
            for (int q = 0; q < 5; ++q)
                s[q] += base[(size_t)q * N2Ae + (zo0 + i + 8) * OO]
                      - base[(size_t)q * N2Ae + (zo0 + i - 1) * OO];
            acc += lncc_val(s, 1.0f / 729.0f);
        }
    }
    block_reduce_store(acc, pA + blk);
}

// B XY from A's XY, vectorized: 2 outputs per thread
__device__ __forceinline__ void bXY_body(int tid, const float* __restrict__ b2a,
                                         float* __restrict__ b2b)
{
    const int total = BATCH * 72 * 28 * 14;          // 112896
    if (tid >= total) return;
    int px = tid % 14;
    int yo = (tid / 14) % 28;
    int p  = tid / 392;
    const float* ib = b2a + (size_t)p * 4096;
    int r0 = 2 * yo * 64, r1 = r0 + 9 * 64;
    #pragma unroll
    for (int q = 0; q < 5; ++q) {
        const float* pq = ib + (size_t)q * N2Ae;
        const float4* row0 = (const float4*)(pq + r0);
        const float4* row1 = (const float4*)(pq + r1);
        float4 a0 = row0[px], b0 = row0[px + 2];
        float4 a1 = row1[px], b1 = row1[px + 2];
        float2 o;
        o.x = a0.x + b0.y + a1.x + b1.y;
        o.y = a0.z + b0.w + a1.z + b1.w;
        *(float2*)(b2b + (size_t)q * N2Be + (size_t)p * 784 + yo * 28 + 2 * px) = o;
    }
}

// C: Y-pass, LDS-staged per (b,z) slice — each b1c element read ONCE from HBM.
__device__ void cYL_body(int blk, const float* __restrict__ b1c,
                         float* __restrict__ b2c, float* lds)
{
    const int t = threadIdx.x;
    #pragma unroll
    for (int q = 0; q < 5; ++q) {
        const float4* src = (const float4*)(b1c + (size_t)q * N1C
                                            + (size_t)blk * 1296);
        float4* dst = (float4*)(lds + q * 1296);
        for (int i = t; i < 324; i += 256) dst[i] = src[i];
    }
    __syncthreads();
    for (int i = t; i < 405; i += 256) {
        int q  = i % 5;
        int xo = (i / 5) % 9;
        int yo = i / 45;
        const float* base = lds + q * 1296 + xo;
        float s = 0.f;
        #pragma unroll
        for (int j = 0; j < 36; ++j) s += base[(9 * yo + 2 * j) * 9];
        b2c[(size_t)q * N2C + ((size_t)blk * 9 + yo) * 9 + xo] = s;
    }
}

constexpr int B_AZ  = (BATCH * 4 * 64 * 64) / 256;       // 256  (CHUNK=16)
constexpr int B_BXY = (BATCH * 72 * 28 * 14) / 256;      // 441
constexpr int B_CYL = BATCH * DIM;                       // 576
constexpr int SM2   = 5 * 1296;                          // 6480 floats

__global__ __launch_bounds__(256) void k2(const float* __restrict__ b2a,
                                          const float* __restrict__ b1c,
                                          float* __restrict__ b2b,
                                          float* __restrict__ b2c,
                                          float* __restrict__ pA)
{
    __shared__ float smem[SM2];
    int blk = blockIdx.x;
    if (blk < B_AZ)              aZ_body(blk, b2a, pA);
    else if (blk < B_AZ + B_BXY) bXY_body((blk - B_AZ) * 256 + threadIdx.x, b2a, b2b);
    else                         cYL_body(blk - B_AZ - B_BXY, b1c, b2c, smem);
}

// ======================= k3 bodies (proven) =================================

__device__ __forceinline__ void bZ_body(int blk, const float* __restrict__ b2b,
                                        float* __restrict__ pB)
{
    int tid = blk * 256 + threadIdx.x;
    float acc = 0.f;
    {
        int sp   = tid & 7;
        int rest = tid >> 3;
        int px = rest % 14;
        int yo = (rest / 14) % 28;
        int zo = (rest / 392) % 28;
        int b  = rest / 10976;
        const int OO = 784;
        const float* base = b2b + (size_t)b * 72 * OO + yo * 28 + 2 * px;

        float sx[5] = {0.f, 0.f, 0.f, 0.f, 0.f};
        float sy[5] = {0.f, 0.f, 0.f, 0.f, 0.f};
        #pragma unroll
        for (int j = 0; j < 18; ++j) {
            if ((j & 7) == sp) {
                #pragma unroll
                for (int q = 0; q < 5; ++q) {
                    float2 v = *(const float2*)(base + (size_t)q * N2Be
                                                + (2 * zo + j) * OO);
                    sx[q] += v.x; sy[q] += v.y;
                }
            }
        }
        #pragma unroll
        for (int off = 1; off < 8; off <<= 1) {
            #pragma unroll
            for (int q = 0; q < 5; ++q) {
                sx[q] += __shfl_xor(sx[q], off, 64);
                sy[q] += __shfl_xor(sy[q], off, 64);
            }
        }
        if (sp == 0)
            acc = lncc_val(sx, 1.0f / 5832.0f) + lncc_val(sy, 1.0f / 5832.0f);
    }
    block_reduce_store(acc, pB + blk);
}

__device__ __forceinline__ void cZ_body(int blk, const float* __restrict__ b2c,
                                        float* __restrict__ pC)
{
    int tid = blk * 256 + threadIdx.x;
    const int total = BATCH * 9 * 9 * 9 * 16;
    float acc = 0.f;
    if (tid < total) {
        int sp   = tid & 15;
        int rest = tid >> 4;
        int xo = rest % 9;
        int yo = (rest / 9) % 9;
        int zo = (rest / 81) % 9;
        int b  = rest / 729;
        const int OO = 81;
        const float* base = b2c + (size_t)b * DIM * OO + yo * 9 + xo;

        float s[5] = {0.f, 0.f, 0.f, 0.f, 0.f};
        #pragma unroll
        for (int j = 0; j < 36; ++j) {
            if ((j & 15) == sp) {
                int z = 9 * zo + 2 * j;
                #pragma unroll
                for (int q = 0; q < 5; ++q) s[q] += base[(size_t)q * N2C + z * OO];
            }
        }
        #pragma unroll
        for (int off = 1; off < 16; off <<= 1) {
            #pragma unroll
            for (int q = 0; q < 5; ++q) s[q] += __shfl_xor(s[q], off, 64);
        }
        if (sp == 0) acc = lncc_val(s, 1.0f / 46656.0f);
    }
    block_reduce_store(acc, pC + blk);
}

constexpr int B_BZ = (BATCH * 28 * 28 * 14 * 8) / 256;     // 1372
constexpr int B_CZ = (BATCH * 9 * 9 * 9 * 16 + 255) / 256; // 183

__global__ __launch_bounds__(256) void k3(const float* __restrict__ b2b,
                                          const float* __restrict__ b2c,
                                          float* __restrict__ pB,
                                          float* __restrict__ pC)
{
    int blk = blockIdx.x;
    if (blk < B_BZ) bZ_body(blk, b2b, pB);
    else            cZ_body(blk - B_BZ, b2c, pC);
}

// ======================= k4: weighted final reduce ==========================

__global__ __launch_bounds__(256) void k4(const float* __restrict__ pA,
                                          const float* __restrict__ pB,
                                          const float* __restrict__ pC,
                                          float* __restrict__ out)
{
    const int t = threadIdx.x;
    float sA = 0.f, sB = 0.f, sC = 0.f;
    for (int i = t; i < B_AZ; i += 256) sA += pA[i];
    for (int i = t; i < B_BZ; i += 256) sB += pB[i];
    for (int i = t; i < B_CZ; i += 256) sC += pC[i];
    float s = (0.1f / 262144.0f) * sA + (0.3f / 21952.0f) * sB
            + (0.6f / 729.0f) * sC;
    #pragma unroll
    for (int off = 32; off > 0; off >>= 1) s += __shfl_down(s, off, 64);
    __shared__ float sm[4];
    int lane = t & 63, wid = t >> 6;
    if (lane == 0) sm[wid] = s;
    __syncthreads();
    if (t == 0) out[0] = 4.0f - (sm[0] + sm[1] + sm[2] + sm[3]);
}

// ============================================================================
extern "C" void kernel_launch(void* const* d_in, const int* in_sizes, int n_in,
                              void* d_out, int out_size, void* d_ws, size_t ws_size,
                              hipStream_t stream) {
    const float* input  = (const float*)d_in[0];
    const float* target = (const float*)d_in[1];
    float* out = (float*)d_out;

    // ws: b2a 23.6MB | b1c 14.9MB | b2b 4.5MB | b2c 0.93MB | partials ~7KB
    float* b2a = (float*)d_ws;
    float* b1c = b2a + (size_t)5 * N2Ae;
    float* b2b = b1c + (size_t)5 * N1C;
    float* b2c = b2b + (size_t)5 * N2Be;
    float* pA  = b2c + (size_t)5 * N2C;
    float* pB  = pA + B_AZ;
    float* pC  = pB + B_BZ;

    k1<<<B_AXY + B_CX, 256, 0, stream>>>(input, target, b2a, b1c);
    k2<<<B_AZ + B_BXY + B_CYL, 256, 0, stream>>>(b2a, b1c, b2b, b2c, pA);
    k3<<<B_BZ + B_CZ, 256, 0, stream>>>(b2b, b2c, pB, pC);
    k4<<<1, 256, 0, stream>>>(pA, pB, pC, out);
}

// Round 17
// 77.819 us; speedup vs baseline: 1.3360x; 1.3360x over previous
//
#include <hip/hip_runtime.h>

// LNCC multi-scale loss, fp32, (4,1,144,144,144) -> scalar.
// A(K=9,ST=2), B(K=18,ST=4): all taps on even coords -> even-grid volume.
//   A = 9^3 box stride 1 on even grid; B = 18^3 = eight 9^3 boxes =>
//   B-XY = 4 adds over A's XY sums (b2a->b2b); B-Z from compact b2b.
// C(K=36,ST=9): cX (k1, LDS-staged) -> cYL (k2, LDS-staged per (b,z)) -> cZ.
// No same-address atomics; reducers write partial[blk]; k4 sums.
// k1: aXY + cX (one input sweep, contiguous role ranges — XCD-friendly)
// k2: aZ CHUNK=16 +LNCC->pA | bXY vec | cYL (LDS, no tap re-reads)
// k3: bZ vec+LNCC->pB | cZ+LNCC->pC
// k4: weighted reduce -> out

constexpr int BATCH = 4;
constexpr int DIM   = 144;
constexpr int NROWS = BATCH * DIM * DIM;        // 82944
constexpr float EPS = 1e-5f;

constexpr int N1C  = NROWS * 9;                 //   746,496 (C X-out)
constexpr int N2Ae = BATCH * 72 * 64 * 64;      // 1,179,648 (A XY-out)
constexpr int N2Be = BATCH * 72 * 28 * 28;      //   225,792 (B XY-out)
constexpr int N2C  = BATCH * DIM * 9 * 9;       //    46,656 (C Y-out)

// ======================= shared device helpers ==============================

__device__ __forceinline__ float lncc_val(const float s[5], float inv_numel) {
    float cross = s[4] - s[0] * s[1] * inv_numel;
    float ivar  = s[2] - s[0] * s[0] * inv_numel;
    float tvar  = s[3] - s[1] * s[1] * inv_numel;
    return (cross * cross) / (ivar * tvar + EPS);
}

__device__ __forceinline__ void block_reduce_store(float acc, float* slot) {
    #pragma unroll
    for (int off = 32; off > 0; off >>= 1) acc += __shfl_down(acc, off, 64);
    __shared__ float sm[4];
    int lane = threadIdx.x & 63, wid = threadIdx.x >> 6;
    if (lane == 0) sm[wid] = acc;
    __syncthreads();
    if (threadIdx.x == 0) *slot = sm[0] + sm[1] + sm[2] + sm[3];
}

// ======================= k1 bodies (R10, proven) ============================

__device__ void aXY_body(int blk, const float* __restrict__ in,
                         const float* __restrict__ tg,
                         float* __restrict__ b2a, float* xs)
{
    const int p  = blk >> 2;            // b*72 + ez
    const int c  = blk & 3;
    const int b  = p / 72;
    const int ez = p % 72;
    const int xo0 = c * 16;
    const size_t gpl = (size_t)(b * DIM + 2 * ez) * (DIM * DIM);
    const int t = threadIdx.x;

    // ---- X: items (yp 0..71, dp 0..7) -> outputs dx0=2dp, dx0+1 ----
    for (int i = t; i < 576; i += 256) {
        int yp = i >> 3, dp = i & 7;
        int dx0 = dp * 2;
        int e0  = xo0 + dx0;
        const float* rowa = in + gpl + (size_t)(2 * yp) * DIM;
        const float* rowb = tg + gpl + (size_t)(2 * yp) * DIM;
        const float4* ga = (const float4*)rowa + (e0 >> 1);
        const float4* gb = (const float4*)rowb + (e0 >> 1);
        float ea[10], eb[10];
        #pragma unroll
        for (int k = 0; k < 5; ++k) {
            float4 A = ga[k]; ea[2 * k] = A.x; ea[2 * k + 1] = A.z;
            float4 B = gb[k]; eb[2 * k] = B.x; eb[2 * k + 1] = B.z;
        }
        float* xr = &xs[yp * 82 + dx0];
        #pragma unroll
        for (int q = 0; q < 5; ++q) {
            float2 sq; sq.x = 0.f; sq.y = 0.f;
            #pragma unroll
            for (int j = 0; j < 9; ++j) {
                float a0 = ea[j],     b0 = eb[j];
                float a1 = ea[j + 1], b1 = eb[j + 1];
                float v0, v1;
                if (q == 0)      { v0 = a0;      v1 = a1; }
                else if (q == 1) { v0 = b0;      v1 = b1; }
                else if (q == 2) { v0 = a0 * a0; v1 = a1 * a1; }
                else if (q == 3) { v0 = b0 * b0; v1 = b1 * b1; }
                else             { v0 = a0 * b0; v1 = a1 * b1; }
                sq.x += v0; sq.y += v1;
            }
            *(float2*)&xr[q * 16] = sq;
        }
    }
    __syncthreads();

    // ---- Y: slide over 16 yo per item; float2 I/O ----
    if (t < 160) {
        int dp = t & 7;
        int ch = (t >> 3) & 3;
        int q  = t >> 5;
        int dx0 = 2 * dp, yo0 = ch * 16;
        const float2* xp2 = (const float2*)xs + ((q * 16 + dx0) >> 1);
        float2 s; s.x = 0.f; s.y = 0.f;
        #pragma unroll
        for (int j = 0; j < 9; ++j) {
            float2 v = xp2[(yo0 + j) * 41];
            s.x += v.x; s.y += v.y;
        }
        float2* ob = (float2*)(b2a + (size_t)q * N2Ae
                               + ((size_t)p * 64 + yo0) * 64 + xo0 + dx0);
        ob[0] = s;
        #pragma unroll
        for (int i2 = 1; i2 < 16; ++i2) {
            float2 vn = xp2[(yo0 + i2 + 8) * 41];
            float2 vo = xp2[(yo0 + i2 - 1) * 41];
            s.x += vn.x - vo.x; s.y += vn.y - vo.y;
            ob[(size_t)i2 * 32] = s;
        }
    }
}

constexpr int CXROWS   = 24;
constexpr int CXSTRIDE = 292;                    // dwords per LDS row

__device__ void cX_body(int blk, const float* __restrict__ in,
                        const float* __restrict__ tg,
                        float* __restrict__ b1c, float* lv)
{
    const int t = threadIdx.x;
    const int row0 = blk * CXROWS;
    const float4* gin = (const float4*)(in + (size_t)row0 * DIM);
    const float4* gtg = (const float4*)(tg + (size_t)row0 * DIM);
    for (int i4 = t; i4 < CXROWS * 36; i4 += 256) {
        int rr = i4 / 36, k = i4 % 36;
        float4 A = gin[i4], B = gtg[i4];
        float4* d = (float4*)&lv[rr * CXSTRIDE + k * 8];
        float4 w0; w0.x = A.x; w0.y = B.x; w0.z = A.y; w0.w = B.y;
        float4 w1; w1.x = A.z; w1.y = B.z; w1.z = A.w; w1.w = B.w;
        d[0] = w0; d[1] = w1;
    }
    __syncthreads();
    if (t < CXROWS * 9) {
        int rr = t / 9, xo = t % 9;
        const float2* pp = (const float2*)&lv[rr * CXSTRIDE] + xo * 9;
        float s0 = 0.f, s1 = 0.f, s2 = 0.f, s3 = 0.f, s4 = 0.f;
        #pragma unroll
        for (int j = 0; j < 36; ++j) {
            float2 ab = pp[2 * j];
            float a = ab.x, bb = ab.y;
            s0 += a; s1 += bb; s2 += a * a; s3 += bb * bb; s4 += a * bb;
        }
        int o = (row0 + rr) * 9 + xo;
        b1c[o] = s0; b1c[N1C + o] = s1; b1c[2 * N1C + o] = s2;
        b1c[3 * N1C + o] = s3; b1c[4 * N1C + o] = s4;
    }
}

constexpr int B_AXY = BATCH * 72 * 4;        // 1152
constexpr int B_CX  = NROWS / CXROWS;        // 3456
constexpr int SM1   = CXROWS * CXSTRIDE;     // 7008 floats (28 KB) >= 72*82

__global__ __launch_bounds__(256) void k1(const float* __restrict__ in,
                                          const float* __restrict__ tg,
                                          float* __restrict__ b2a,
                                          float* __restrict__ b1c)
{
    __shared__ float smem[SM1];
    int blk = blockIdx.x;
    if (blk < B_AXY) aXY_body(blk, in, tg, b2a, smem);
    else             cX_body(blk - B_AXY, in, tg, b1c, smem);
}

// ======================= k2 bodies ==========================================

// A: Z box-sum + LNCC, sliding CHUNK=16 (read redundancy 1.5x) -> pA[blk]
__device__ __forceinline__ void aZ_body(int blk, const float* __restrict__ b2a,
                                        float* __restrict__ pA)
{
    int tid = blk * 256 + threadIdx.x;
    float acc = 0.f;
    {
        int xo = tid & 63;
        int yo = (tid >> 6) & 63;
        int ch = (tid >> 12) & 3;
        int b  = tid >> 14;
        const int zo0 = ch * 16;
        const int OO = 64 * 64;
        const float* base = b2a + (size_t)b * 72 * OO + yo * 64 + xo;

        float s[5] = {0.f, 0.f, 0.f, 0.f, 0.f};
        #pragma unroll
        for (int j = 0; j < 9; ++j) {
            #pragma unroll
            for (int q = 0; q < 5; ++q)
                s[q] += base[(size_t)q * N2Ae + (zo0 + j) * OO];
        }
        acc += lncc_val(s, 1.0f / 729.0f);
        #pragma unroll
        for (int i = 1; i < 16; ++i) {
            #pragma unroll
            for (int q = 0; q < 5; ++q)
                s[q] += base[(size_t)q * N2Ae + (zo0 + i + 8) * OO]
                      - base[(size_t)q * N2Ae + (zo0 + i - 1) * OO];
            acc += lncc_val(s, 1.0f / 729.0f);
        }
    }
    block_reduce_store(acc, pA + blk);
}

// B XY from A's XY, vectorized: 2 outputs per thread
__device__ __forceinline__ void bXY_body(int tid, const float* __restrict__ b2a,
                                         float* __restrict__ b2b)
{
    const int total = BATCH * 72 * 28 * 14;          // 112896
    if (tid >= total) return;
    int px = tid % 14;
    int yo = (tid / 14) % 28;
    int p  = tid / 392;
    const float* ib = b2a + (size_t)p * 4096;
    int r0 = 2 * yo * 64, r1 = r0 + 9 * 64;
    #pragma unroll
    for (int q = 0; q < 5; ++q) {
        const float* pq = ib + (size_t)q * N2Ae;
        const float4* row0 = (const float4*)(pq + r0);
        const float4* row1 = (const float4*)(pq + r1);
        float4 a0 = row0[px], b0 = row0[px + 2];
        float4 a1 = row1[px], b1 = row1[px + 2];
        float2 o;
        o.x = a0.x + b0.y + a1.x + b1.y;
        o.y = a0.z + b0.w + a1.z + b1.w;
        *(float2*)(b2b + (size_t)q * N2Be + (size_t)p * 784 + yo * 28 + 2 * px) = o;
    }
}

// C: Y-pass, LDS-staged per (b,z) slice — each b1c element read ONCE from HBM.
__device__ void cYL_body(int blk, const float* __restrict__ b1c,
                         float* __restrict__ b2c, float* lds)
{
    const int t = threadIdx.x;
    #pragma unroll
    for (int q = 0; q < 5; ++q) {
        const float4* src = (const float4*)(b1c + (size_t)q * N1C
                                            + (size_t)blk * 1296);
        float4* dst = (float4*)(lds + q * 1296);
        for (int i = t; i < 324; i += 256) dst[i] = src[i];
    }
    __syncthreads();
    for (int i = t; i < 405; i += 256) {
        int q  = i % 5;
        int xo = (i / 5) % 9;
        int yo = i / 45;
        const float* base = lds + q * 1296 + xo;
        float s = 0.f;
        #pragma unroll
        for (int j = 0; j < 36; ++j) s += base[(9 * yo + 2 * j) * 9];
        b2c[(size_t)q * N2C + ((size_t)blk * 9 + yo) * 9 + xo] = s;
    }
}

constexpr int B_AZ  = (BATCH * 4 * 64 * 64) / 256;       // 256  (CHUNK=16)
constexpr int B_BXY = (BATCH * 72 * 28 * 14) / 256;      // 441
constexpr int B_CYL = BATCH * DIM;                       // 576
constexpr int SM2   = 5 * 1296;                          // 6480 floats

__global__ __launch_bounds__(256) void k2(const float* __restrict__ b2a,
                                          const float* __restrict__ b1c,
                                          float* __restrict__ b2b,
                                          float* __restrict__ b2c,
                                          float* __restrict__ pA)
{
    __shared__ float smem[SM2];
    int blk = blockIdx.x;
    if (blk < B_AZ)              aZ_body(blk, b2a, pA);
    else if (blk < B_AZ + B_BXY) bXY_body((blk - B_AZ) * 256 + threadIdx.x, b2a, b2b);
    else                         cYL_body(blk - B_AZ - B_BXY, b1c, b2c, smem);
}

// ======================= k3 bodies (proven) =================================

__device__ __forceinline__ void bZ_body(int blk, const float* __restrict__ b2b,
                                        float* __restrict__ pB)
{
    int tid = blk * 256 + threadIdx.x;
    float acc = 0.f;
    {
        int sp   = tid & 7;
        int rest = tid >> 3;
        int px = rest % 14;
        int yo = (rest / 14) % 28;
        int zo = (rest / 392) % 28;
        int b  = rest / 10976;
        const int OO = 784;
        const float* base = b2b + (size_t)b * 72 * OO + yo * 28 + 2 * px;

        float sx[5] = {0.f, 0.f, 0.f, 0.f, 0.f};
        float sy[5] = {0.f, 0.f, 0.f, 0.f, 0.f};
        #pragma unroll
        for (int j = 0; j < 18; ++j) {
            if ((j & 7) == sp) {
                #pragma unroll
                for (int q = 0; q < 5; ++q) {
                    float2 v = *(const float2*)(base + (size_t)q * N2Be
                                                + (2 * zo + j) * OO);
                    sx[q] += v.x; sy[q] += v.y;
                }
            }
        }
        #pragma unroll
        for (int off = 1; off < 8; off <<= 1) {
            #pragma unroll
            for (int q = 0; q < 5; ++q) {
                sx[q] += __shfl_xor(sx[q], off, 64);
                sy[q] += __shfl_xor(sy[q], off, 64);
            }
        }
        if (sp == 0)
            acc = lncc_val(sx, 1.0f / 5832.0f) + lncc_val(sy, 1.0f / 5832.0f);
    }
    block_reduce_store(acc, pB + blk);
}

__device__ __forceinline__ void cZ_body(int blk, const float* __restrict__ b2c,
                                        float* __restrict__ pC)
{
    int tid = blk * 256 + threadIdx.x;
    const int total = BATCH * 9 * 9 * 9 * 16;
    float acc = 0.f;
    if (tid < total) {
        int sp   = tid & 15;
        int rest = tid >> 4;
        int xo = rest % 9;
        int yo = (rest / 9) % 9;
        int zo = (rest / 81) % 9;
        int b  = rest / 729;
        const int OO = 81;
        const float* base = b2c + (size_t)b * DIM * OO + yo * 9 + xo;

        float s[5] = {0.f, 0.f, 0.f, 0.f, 0.f};
        #pragma unroll
        for (int j = 0; j < 36; ++j) {
            if ((j & 15) == sp) {
                int z = 9 * zo + 2 * j;
                #pragma unroll
                for (int q = 0; q < 5; ++q) s[q] += base[(size_t)q * N2C + z * OO];
            }
        }
        #pragma unroll
        for (int off = 1; off < 16; off <<= 1) {
            #pragma unroll
            for (int q = 0; q < 5; ++q) s[q] += __shfl_xor(s[q], off, 64);
        }
        if (sp == 0) acc = lncc_val(s, 1.0f / 46656.0f);
    }
    block_reduce_store(acc, pC + blk);
}

constexpr int B_BZ = (BATCH * 28 * 28 * 14 * 8) / 256;     // 1372
constexpr int B_CZ = (BATCH * 9 * 9 * 9 * 16 + 255) / 256; // 183

__global__ __launch_bounds__(256) void k3(const float* __restrict__ b2b,
                                          const float* __restrict__ b2c,
                                          float* __restrict__ pB,
                                          float* __restrict__ pC)
{
    int blk = blockIdx.x;
    if (blk < B_BZ) bZ_body(blk, b2b, pB);
    else            cZ_body(blk - B_BZ, b2c, pC);
}

// ======================= k4: weighted final reduce ==========================

__global__ __launch_bounds__(256) void k4(const float* __restrict__ pA,
                                          const float* __restrict__ pB,
                                          const float* __restrict__ pC,
                                          float* __restrict__ out)
{
    const int t = threadIdx.x;
    float sA = 0.f, sB = 0.f, sC = 0.f;
    for (int i = t; i < B_AZ; i += 256) sA += pA[i];
    for (int i = t; i < B_BZ; i += 256) sB += pB[i];
    for (int i = t; i < B_CZ; i += 256) sC += pC[i];
    float s = (0.1f / 262144.0f) * sA + (0.3f / 21952.0f) * sB
            + (0.6f / 729.0f) * sC;
    #pragma unroll
    for (int off = 32; off > 0; off >>= 1) s += __shfl_down(s, off, 64);
    __shared__ float sm[4];
    int lane = t & 63, wid = t >> 6;
    if (lane == 0) sm[wid] = s;
    __syncthreads();
    if (t == 0) out[0] = 4.0f - (sm[0] + sm[1] + sm[2] + sm[3]);
}

// ============================================================================
extern "C" void kernel_launch(void* const* d_in, const int* in_sizes, int n_in,
                              void* d_out, int out_size, void* d_ws, size_t ws_size,
                              hipStream_t stream) {
    const float* input  = (const float*)d_in[0];
    const float* target = (const float*)d_in[1];
    float* out = (float*)d_out;

    // ws: b2a 23.6MB | b1c 14.9MB | b2b 4.5MB | b2c 0.93MB | partials ~7KB
    float* b2a = (float*)d_ws;
    float* b1c = b2a + (size_t)5 * N2Ae;
    float* b2b = b1c + (size_t)5 * N1C;
    float* b2c = b2b + (size_t)5 * N2Be;
    float* pA  = b2c + (size_t)5 * N2C;
    float* pB  = pA + B_AZ;
    float* pC  = pB + B_BZ;

    k1<<<B_AXY + B_CX, 256, 0, stream>>>(input, target, b2a, b1c);
    k2<<<B_AZ + B_BXY + B_CYL, 256, 0, stream>>>(b2a, b1c, b2b, b2c, pA);
    k3<<<B_BZ + B_CZ, 256, 0, stream>>>(b2b, b2c, pB, pC);
    k4<<<1, 256, 0, stream>>>(pA, pB, pC, out);
}